// Round 1
// baseline (371.427 us; speedup 1.0000x reference)
//
#include <hip/hip_runtime.h>
#include <hip/hip_bf16.h>
#include <stdint.h>

typedef __bf16 bf16x8 __attribute__((ext_vector_type(8)));
typedef float f32x4 __attribute__((ext_vector_type(4)));
typedef unsigned short ushort_t;
typedef ushort_t ushort8 __attribute__((ext_vector_type(8)));

#define GLDS16(g, l) __builtin_amdgcn_global_load_lds(                          \
    (const __attribute__((address_space(1))) void*)(g),                         \
    (__attribute__((address_space(3))) void*)(l), 16, 0, 0)

__device__ __constant__ float NF4_LUT_C[16] = {
    -1.0f, -0.6961928009986877f, -0.5250730514526367f, -0.39491748809814453f,
    -0.28444138169288635f, -0.18477343022823334f, -0.09105003625154495f, 0.0f,
    0.07958029955625534f, 0.16093020141124725f, 0.24611230194568634f,
    0.33791524171829224f, 0.44070982933044434f, 0.5626170039176941f,
    0.7229568362236023f, 1.0f};

__device__ inline ushort_t f32_to_bf16(float f) {
    uint32_t u = __builtin_bit_cast(uint32_t, f);
    u += 0x7FFFu + ((u >> 16) & 1u);
    return (ushort_t)(u >> 16);
}

// ---------------------------------------------------------------------------
// Kernel 1: cast x (fp32) -> bf16, 8 elems/thread
// ---------------------------------------------------------------------------
__global__ __launch_bounds__(256) void cast_x_kernel(
    const float* __restrict__ x, ushort_t* __restrict__ xb)
{
    const int i = blockIdx.x * 256 + threadIdx.x;   // 8 elements per thread
    const float4* p = reinterpret_cast<const float4*>(x);
    float4 a = p[i * 2];
    float4 b = p[i * 2 + 1];
    ushort8 v;
    v[0] = f32_to_bf16(a.x); v[1] = f32_to_bf16(a.y);
    v[2] = f32_to_bf16(a.z); v[3] = f32_to_bf16(a.w);
    v[4] = f32_to_bf16(b.x); v[5] = f32_to_bf16(b.y);
    v[6] = f32_to_bf16(b.z); v[7] = f32_to_bf16(b.w);
    *reinterpret_cast<ushort8*>(xb + (size_t)i * 8) = v;
}

// ---------------------------------------------------------------------------
// Kernel 2: NF4 dequant + transpose.
// W flat index i = k*4096 + n (k = D_IN row, n = D_OUT col); byte i/2,
// high nibble = even i; scale index = i/64. Output Wt[n][k] bf16.
// Each block: one 64(k) x 64(n) tile.
// ---------------------------------------------------------------------------
__global__ __launch_bounds__(256) void nf4_dequant_t_kernel(
    const int* __restrict__ q, const float* __restrict__ scales,
    ushort_t* __restrict__ Wt)
{
    __shared__ float lut[16];
    __shared__ ushort_t tile[64][65];   // [k_local][n_local], padded
    const int t = threadIdx.x;
    if (t < 16) lut[t] = NF4_LUT_C[t];
    __syncthreads();

    const int nt = blockIdx.x & 63;
    const int kt = blockIdx.x >> 6;

    // load+dequant: 512 int4 loads (each = 4 int32 byte-entries = 8 values)
    #pragma unroll
    for (int L = t; L < 512; L += 256) {
        const int r  = L >> 3;     // k_local
        const int qd = L & 7;      // quad within row
        const int k  = kt * 64 + r;
        const int4 e4 = *reinterpret_cast<const int4*>(q + (size_t)k * 2048 + nt * 32 + qd * 4);
        const float s = scales[k * 64 + nt];
        const int nb = qd * 8;
        int bts[4] = {e4.x, e4.y, e4.z, e4.w};
        #pragma unroll
        for (int e = 0; e < 4; ++e) {
            const int byte = bts[e];
            tile[r][nb + e * 2]     = f32_to_bf16(lut[(byte >> 4) & 0xF] * s);
            tile[r][nb + e * 2 + 1] = f32_to_bf16(lut[byte & 0xF] * s);
        }
    }
    __syncthreads();

    // write out transposed: thread -> row n_local = t>>2, k chunk (t&3)*16
    const int nl = t >> 2;
    const int ks = (t & 3) * 16;
    ushort8 v0, v1;
    #pragma unroll
    for (int j = 0; j < 8; ++j) v0[j] = tile[ks + j][nl];
    #pragma unroll
    for (int j = 0; j < 8; ++j) v1[j] = tile[ks + 8 + j][nl];
    ushort_t* dst = Wt + (size_t)(nt * 64 + nl) * 4096 + kt * 64 + ks;
    *reinterpret_cast<ushort8*>(dst)     = v0;
    *reinterpret_cast<ushort8*>(dst + 8) = v1;
}

// ---------------------------------------------------------------------------
// Kernel 3: bf16 GEMM, m97 structure. C[8192][4096] = A[8192][4096] * B,
// B given as Bt[n][k]. 128x128 tile, BK=32, 4 waves (2x2), 4x4 frags of
// 16x16x32 per wave. global_load_lds width-16 staging, 2 barriers/K-step.
// ---------------------------------------------------------------------------
__global__ __launch_bounds__(256) void gemm_nf4_kernel(
    const ushort_t* __restrict__ A, const ushort_t* __restrict__ Bt,
    const float* __restrict__ bias, float* __restrict__ C)
{
    __shared__ __align__(16) ushort_t As[128 * 32];
    __shared__ __align__(16) ushort_t Bs[128 * 32];

    const int tid  = threadIdx.x;
    const int lane = tid & 63;
    const int wave = tid >> 6;
    const int wm = (wave >> 1) * 64;   // wave row offset in tile
    const int wn = (wave & 1) * 64;    // wave col offset in tile
    const int m0 = blockIdx.y * 128;
    const int n0 = blockIdx.x * 128;

    // per-lane global staging pointers (16B per lane, 4 lanes per row)
    const ushort_t* gA = A  + (size_t)(m0 + wave * 32 + (lane >> 2)) * 4096 + (lane & 3) * 8;
    const ushort_t* gB = Bt + (size_t)(n0 + wave * 32 + (lane >> 2)) * 4096 + (lane & 3) * 8;
    ushort_t* lA0 = &As[(wave * 32) * 32];
    ushort_t* lA1 = &As[(wave * 32 + 16) * 32];
    ushort_t* lB0 = &Bs[(wave * 32) * 32];
    ushort_t* lB1 = &Bs[(wave * 32 + 16) * 32];

    f32x4 acc[4][4];
    #pragma unroll
    for (int i = 0; i < 4; ++i)
        #pragma unroll
        for (int j = 0; j < 4; ++j)
            acc[i][j] = (f32x4){0.f, 0.f, 0.f, 0.f};

    const int arow = wm + (lane & 15);
    const int brow = wn + (lane & 15);
    const int koff = (lane >> 4) * 8;

    for (int k0 = 0; k0 < 4096; k0 += 32) {
        __syncthreads();   // previous compute done before overwriting LDS
        GLDS16(gA + k0,             lA0);
        GLDS16(gA + k0 + 16 * 4096, lA1);
        GLDS16(gB + k0,             lB0);
        GLDS16(gB + k0 + 16 * 4096, lB1);
        __syncthreads();   // vmcnt(0) drain: tiles staged

        bf16x8 af[4], bf[4];
        #pragma unroll
        for (int i = 0; i < 4; ++i) {
            af[i] = *reinterpret_cast<const bf16x8*>(&As[(arow + i * 16) * 32 + koff]);
            bf[i] = *reinterpret_cast<const bf16x8*>(&Bs[(brow + i * 16) * 32 + koff]);
        }
        #pragma unroll
        for (int i = 0; i < 4; ++i)
            #pragma unroll
            for (int j = 0; j < 4; ++j)
                acc[i][j] = __builtin_amdgcn_mfma_f32_16x16x32_bf16(af[i], bf[j], acc[i][j], 0, 0, 0);
    }

    // epilogue: C/D layout col = lane&15, row = (lane>>4)*4 + v  (m89-verified)
    #pragma unroll
    for (int j = 0; j < 4; ++j) {
        const int c = n0 + wn + j * 16 + (lane & 15);
        const float bv = bias[c];
        #pragma unroll
        for (int i = 0; i < 4; ++i) {
            const int r0 = m0 + wm + i * 16 + (lane >> 4) * 4;
            #pragma unroll
            for (int v = 0; v < 4; ++v)
                C[(size_t)(r0 + v) * 4096 + c] = acc[i][j][v] + bv;
        }
    }
}

// ---------------------------------------------------------------------------
extern "C" void kernel_launch(void* const* d_in, const int* in_sizes, int n_in,
                              void* d_out, int out_size, void* d_ws, size_t ws_size,
                              hipStream_t stream) {
    const float* x      = (const float*)d_in[0];   // [4,2048,4096] fp32
    const int*   q      = (const int*)d_in[1];     // [8388608] byte values
    const float* scales = (const float*)d_in[2];   // [262144]
    const float* bias   = (const float*)d_in[3];   // [4096]
    float* out = (float*)d_out;                    // [8192][4096] fp32

    ushort_t* xb = (ushort_t*)d_ws;                                  // 64 MB bf16 x
    ushort_t* Wt = (ushort_t*)((char*)d_ws + (size_t)64 * 1024 * 1024); // 32 MB bf16 W^T

    cast_x_kernel<<<16384, 256, 0, stream>>>(x, xb);
    nf4_dequant_t_kernel<<<4096, 256, 0, stream>>>(q, scales, Wt);
    gemm_nf4_kernel<<<dim3(32, 64), 256, 0, stream>>>(xb, Wt, bias, out);
}

// Round 2
// 333.851 us; speedup vs baseline: 1.1126x; 1.1126x over previous
//
#include <hip/hip_runtime.h>
#include <hip/hip_bf16.h>
#include <stdint.h>

typedef __bf16 bf16x8 __attribute__((ext_vector_type(8)));
typedef float f32x4 __attribute__((ext_vector_type(4)));
typedef unsigned short ushort_t;
typedef ushort_t ushort8 __attribute__((ext_vector_type(8)));

#define GLDS16(g, l) __builtin_amdgcn_global_load_lds(                          \
    (const __attribute__((address_space(1))) void*)(g),                         \
    (__attribute__((address_space(3))) void*)(l), 16, 0, 0)

__device__ __constant__ float NF4_LUT_C[16] = {
    -1.0f, -0.6961928009986877f, -0.5250730514526367f, -0.39491748809814453f,
    -0.28444138169288635f, -0.18477343022823334f, -0.09105003625154495f, 0.0f,
    0.07958029955625534f, 0.16093020141124725f, 0.24611230194568634f,
    0.33791524171829224f, 0.44070982933044434f, 0.5626170039176941f,
    0.7229568362236023f, 1.0f};

__device__ inline ushort_t f32_to_bf16(float f) {
    uint32_t u = __builtin_bit_cast(uint32_t, f);
    u += 0x7FFFu + ((u >> 16) & 1u);
    return (ushort_t)(u >> 16);
}

// ---------------------------------------------------------------------------
// Kernel 1: cast x (fp32) -> bf16, 8 elems/thread
// ---------------------------------------------------------------------------
__global__ __launch_bounds__(256) void cast_x_kernel(
    const float* __restrict__ x, ushort_t* __restrict__ xb)
{
    const int i = blockIdx.x * 256 + threadIdx.x;   // 8 elements per thread
    const float4* p = reinterpret_cast<const float4*>(x);
    float4 a = p[i * 2];
    float4 b = p[i * 2 + 1];
    ushort8 v;
    v[0] = f32_to_bf16(a.x); v[1] = f32_to_bf16(a.y);
    v[2] = f32_to_bf16(a.z); v[3] = f32_to_bf16(a.w);
    v[4] = f32_to_bf16(b.x); v[5] = f32_to_bf16(b.y);
    v[6] = f32_to_bf16(b.z); v[7] = f32_to_bf16(b.w);
    *reinterpret_cast<ushort8*>(xb + (size_t)i * 8) = v;
}

// ---------------------------------------------------------------------------
// Kernel 2: NF4 dequant + transpose -> Wt[n][k] bf16  (unchanged, verified)
// ---------------------------------------------------------------------------
__global__ __launch_bounds__(256) void nf4_dequant_t_kernel(
    const int* __restrict__ q, const float* __restrict__ scales,
    ushort_t* __restrict__ Wt)
{
    __shared__ float lut[16];
    __shared__ ushort_t tile[64][65];   // [k_local][n_local], padded
    const int t = threadIdx.x;
    if (t < 16) lut[t] = NF4_LUT_C[t];
    __syncthreads();

    const int nt = blockIdx.x & 63;
    const int kt = blockIdx.x >> 6;

    #pragma unroll
    for (int L = t; L < 512; L += 256) {
        const int r  = L >> 3;     // k_local
        const int qd = L & 7;      // quad within row
        const int k  = kt * 64 + r;
        const int4 e4 = *reinterpret_cast<const int4*>(q + (size_t)k * 2048 + nt * 32 + qd * 4);
        const float s = scales[k * 64 + nt];
        const int nb = qd * 8;
        int bts[4] = {e4.x, e4.y, e4.z, e4.w};
        #pragma unroll
        for (int e = 0; e < 4; ++e) {
            const int byte = bts[e];
            tile[r][nb + e * 2]     = f32_to_bf16(lut[(byte >> 4) & 0xF] * s);
            tile[r][nb + e * 2 + 1] = f32_to_bf16(lut[byte & 0xF] * s);
        }
    }
    __syncthreads();

    const int nl = t >> 2;
    const int ks = (t & 3) * 16;
    ushort8 v0, v1;
    #pragma unroll
    for (int j = 0; j < 8; ++j) v0[j] = tile[ks + j][nl];
    #pragma unroll
    for (int j = 0; j < 8; ++j) v1[j] = tile[ks + 8 + j][nl];
    ushort_t* dst = Wt + (size_t)(nt * 64 + nl) * 4096 + kt * 64 + ks;
    *reinterpret_cast<ushort8*>(dst)     = v0;
    *reinterpret_cast<ushort8*>(dst + 8) = v1;
}

// ---------------------------------------------------------------------------
// Kernel 3: bf16 GEMM, 256x256 tile, BK=64, 8 waves (2M x 4N), depth-2
// prefetch with counted vmcnt(8), XOR slot-swizzled LDS, setprio MFMA.
// A[8192][4096], Bt[4096][4096] (both K-contiguous bf16). C fp32 + bias.
// ---------------------------------------------------------------------------
// LDS swizzle: logical (row, kslot s in 0..7 of 16B) stored at phys slot
// s ^ (row&7). global_load_lds writes linearly (lane*16B), so the SOURCE
// address is pre-swizzled per-lane (rule #21: both-sides XOR involution).

__device__ __forceinline__ void stage_tile(
    const ushort_t* __restrict__ A, const ushort_t* __restrict__ Bt,
    ushort_t (*Asb)[128 * 64], ushort_t (*Bsb)[128 * 64],
    int m0, int n0, int k0, int wid, int lane)
{
    const int lrow = lane >> 3;                              // 0..7
    const int kswz = k0 + (((lane & 7) ^ lrow) << 3);        // pre-swizzled k
    #pragma unroll
    for (int r = 0; r < 4; ++r) {
        const int row = r * 64 + wid * 8;                    // wave-uniform
        GLDS16(A + (size_t)(m0 + row + lrow) * 4096 + kswz,
               &Asb[r >> 1][(row & 127) * 64]);
    }
    #pragma unroll
    for (int r = 0; r < 4; ++r) {
        const int row = r * 64 + wid * 8;
        GLDS16(Bt + (size_t)(n0 + row + lrow) * 4096 + kswz,
               &Bsb[r >> 1][(row & 127) * 64]);
    }
}

__global__ __launch_bounds__(512, 2) void gemm_nf4_kernel(
    const ushort_t* __restrict__ A, const ushort_t* __restrict__ Bt,
    const float* __restrict__ bias, float* __restrict__ C)
{
    __shared__ __align__(16) ushort_t As[2][2][128 * 64];   // [buf][half][...]
    __shared__ __align__(16) ushort_t Bs[2][2][128 * 64];

    const int tid  = threadIdx.x;
    const int lane = tid & 63;
    const int wid  = tid >> 6;        // 0..7
    const int wr   = wid >> 2;        // 0..1 -> A-half, 128 rows
    const int wc   = wid & 3;         // 0..3 -> 64-col strip
    const int ln15 = lane & 15;
    const int ln7  = lane & 7;
    const int lq   = lane >> 4;       // 0..3

    // XCD-aware bijective swizzle (512 % 8 == 0)
    const int wg  = blockIdx.x;
    const int swz = (wg & 7) * 64 + (wg >> 3);
    const int m0  = (swz >> 4) * 256;   // 32 m-tiles
    const int n0  = (swz & 15) * 256;   // 16 n-tiles

    f32x4 acc[8][4];
    #pragma unroll
    for (int i = 0; i < 8; ++i)
        #pragma unroll
        for (int j = 0; j < 4; ++j)
            acc[i][j] = (f32x4){0.f, 0.f, 0.f, 0.f};

    // prologue: stage tiles 0,1; wait tile 0 (8 younger = tile 1 in flight)
    stage_tile(A, Bt, As[0], Bs[0], m0, n0, 0,  wid, lane);
    stage_tile(A, Bt, As[1], Bs[1], m0, n0, 64, wid, lane);
    asm volatile("s_waitcnt vmcnt(8)" ::: "memory");
    __builtin_amdgcn_s_barrier();
    asm volatile("" ::: "memory");
    __builtin_amdgcn_sched_barrier(0);

    int p = 0;
    for (int t = 0; t < 64; ++t) {
        const ushort_t* Ah = As[p][wr];
        const ushort_t* Bh = Bs[p][wc >> 1];
        const int brow0 = (wc & 1) * 64;

        #pragma unroll
        for (int kk = 0; kk < 2; ++kk) {
            const int s = kk * 4 + lq;
            const int po = ((s ^ ln7) << 3);   // phys slot offset (ushorts)
            bf16x8 bf[4];
            #pragma unroll
            for (int j = 0; j < 4; ++j) {
                const int r = brow0 + j * 16 + ln15;
                bf[j] = *reinterpret_cast<const bf16x8*>(Bh + r * 64 + po);
            }
            #pragma unroll
            for (int mq = 0; mq < 2; ++mq) {
                bf16x8 af[4];
                #pragma unroll
                for (int i = 0; i < 4; ++i) {
                    const int r = mq * 64 + i * 16 + ln15;
                    af[i] = *reinterpret_cast<const bf16x8*>(Ah + r * 64 + po);
                }
                __builtin_amdgcn_s_setprio(1);
                #pragma unroll
                for (int i = 0; i < 4; ++i)
                    #pragma unroll
                    for (int j = 0; j < 4; ++j)
                        acc[mq * 4 + i][j] = __builtin_amdgcn_mfma_f32_16x16x32_bf16(
                            af[i], bf[j], acc[mq * 4 + i][j], 0, 0, 0);
                __builtin_amdgcn_s_setprio(0);
            }
        }

        // all waves done reading buf p
        asm volatile("" ::: "memory");
        __builtin_amdgcn_s_barrier();
        __builtin_amdgcn_sched_barrier(0);
        if (t + 2 < 64) {
            stage_tile(A, Bt, As[p], Bs[p], m0, n0, (t + 2) * 64, wid, lane);
            asm volatile("s_waitcnt vmcnt(8)" ::: "memory");   // tile t+1 landed
        } else {
            asm volatile("s_waitcnt vmcnt(0)" ::: "memory");   // tail drain
        }
        __builtin_amdgcn_s_barrier();
        asm volatile("" ::: "memory");
        __builtin_amdgcn_sched_barrier(0);
        p ^= 1;
    }

    // epilogue: C/D layout col = lane&15, row = (lane>>4)*4 + v
    const int crow0 = m0 + wr * 128 + lq * 4;
    const int ccol0 = n0 + wc * 64 + ln15;
    #pragma unroll
    for (int j = 0; j < 4; ++j) {
        const int c = ccol0 + j * 16;
        const float bv = bias[c];
        #pragma unroll
        for (int i = 0; i < 8; ++i) {
            const int r0 = crow0 + i * 16;
            #pragma unroll
            for (int v = 0; v < 4; ++v)
                C[(size_t)(r0 + v) * 4096 + c] = acc[i][j][v] + bv;
        }
    }
}

// ---------------------------------------------------------------------------
extern "C" void kernel_launch(void* const* d_in, const int* in_sizes, int n_in,
                              void* d_out, int out_size, void* d_ws, size_t ws_size,
                              hipStream_t stream) {
    const float* x      = (const float*)d_in[0];   // [4,2048,4096] fp32
    const int*   q      = (const int*)d_in[1];     // [8388608] byte values
    const float* scales = (const float*)d_in[2];   // [262144]
    const float* bias   = (const float*)d_in[3];   // [4096]
    float* out = (float*)d_out;                    // [8192][4096] fp32

    ushort_t* xb = (ushort_t*)d_ws;                                     // 64 MB bf16 x
    ushort_t* Wt = (ushort_t*)((char*)d_ws + (size_t)64 * 1024 * 1024); // 32 MB bf16 W^T

    cast_x_kernel<<<16384, 256, 0, stream>>>(x, xb);
    nf4_dequant_t_kernel<<<4096, 256, 0, stream>>>(q, scales, Wt);
    gemm_nf4_kernel<<<512, 512, 0, stream>>>(xb, Wt, bias, out);
}

// Round 3
// 327.719 us; speedup vs baseline: 1.1334x; 1.0187x over previous
//
#include <hip/hip_runtime.h>
#include <hip/hip_bf16.h>
#include <stdint.h>

typedef __bf16 bf16x8 __attribute__((ext_vector_type(8)));
typedef float f32x4 __attribute__((ext_vector_type(4)));
typedef unsigned short ushort_t;
typedef ushort_t ushort8 __attribute__((ext_vector_type(8)));

#define GLDS16(g, l) __builtin_amdgcn_global_load_lds(                          \
    (const __attribute__((address_space(1))) void*)(g),                         \
    (__attribute__((address_space(3))) void*)(l), 16, 0, 0)

__device__ __constant__ float NF4_LUT_C[16] = {
    -1.0f, -0.6961928009986877f, -0.5250730514526367f, -0.39491748809814453f,
    -0.28444138169288635f, -0.18477343022823334f, -0.09105003625154495f, 0.0f,
    0.07958029955625534f, 0.16093020141124725f, 0.24611230194568634f,
    0.33791524171829224f, 0.44070982933044434f, 0.5626170039176941f,
    0.7229568362236023f, 1.0f};

__device__ inline ushort_t f32_to_bf16(float f) {
    uint32_t u = __builtin_bit_cast(uint32_t, f);
    u += 0x7FFFu + ((u >> 16) & 1u);
    return (ushort_t)(u >> 16);
}

// ---------------------------------------------------------------------------
// Kernel 1: cast x (fp32) -> bf16, 8 elems/thread
// ---------------------------------------------------------------------------
__global__ __launch_bounds__(256) void cast_x_kernel(
    const float* __restrict__ x, ushort_t* __restrict__ xb)
{
    const int i = blockIdx.x * 256 + threadIdx.x;
    const float4* p = reinterpret_cast<const float4*>(x);
    float4 a = p[i * 2];
    float4 b = p[i * 2 + 1];
    ushort8 v;
    v[0] = f32_to_bf16(a.x); v[1] = f32_to_bf16(a.y);
    v[2] = f32_to_bf16(a.z); v[3] = f32_to_bf16(a.w);
    v[4] = f32_to_bf16(b.x); v[5] = f32_to_bf16(b.y);
    v[6] = f32_to_bf16(b.z); v[7] = f32_to_bf16(b.w);
    *reinterpret_cast<ushort8*>(xb + (size_t)i * 8) = v;
}

// ---------------------------------------------------------------------------
// Kernel 2: NF4 dequant + transpose -> Wt[n][k] bf16  (unchanged, verified)
// ---------------------------------------------------------------------------
__global__ __launch_bounds__(256) void nf4_dequant_t_kernel(
    const int* __restrict__ q, const float* __restrict__ scales,
    ushort_t* __restrict__ Wt)
{
    __shared__ float lut[16];
    __shared__ ushort_t tile[64][65];
    const int t = threadIdx.x;
    if (t < 16) lut[t] = NF4_LUT_C[t];
    __syncthreads();

    const int nt = blockIdx.x & 63;
    const int kt = blockIdx.x >> 6;

    #pragma unroll
    for (int L = t; L < 512; L += 256) {
        const int r  = L >> 3;
        const int qd = L & 7;
        const int k  = kt * 64 + r;
        const int4 e4 = *reinterpret_cast<const int4*>(q + (size_t)k * 2048 + nt * 32 + qd * 4);
        const float s = scales[k * 64 + nt];
        const int nb = qd * 8;
        int bts[4] = {e4.x, e4.y, e4.z, e4.w};
        #pragma unroll
        for (int e = 0; e < 4; ++e) {
            const int byte = bts[e];
            tile[r][nb + e * 2]     = f32_to_bf16(lut[(byte >> 4) & 0xF] * s);
            tile[r][nb + e * 2 + 1] = f32_to_bf16(lut[byte & 0xF] * s);
        }
    }
    __syncthreads();

    const int nl = t >> 2;
    const int ks = (t & 3) * 16;
    ushort8 v0, v1;
    #pragma unroll
    for (int j = 0; j < 8; ++j) v0[j] = tile[ks + j][nl];
    #pragma unroll
    for (int j = 0; j < 8; ++j) v1[j] = tile[ks + 8 + j][nl];
    ushort_t* dst = Wt + (size_t)(nt * 64 + nl) * 4096 + kt * 64 + ks;
    *reinterpret_cast<ushort8*>(dst)     = v0;
    *reinterpret_cast<ushort8*>(dst + 8) = v1;
}

// ---------------------------------------------------------------------------
// Kernel 3: bf16 GEMM, 256x256 tile, BK=32, 8 waves (2M x 4N).
// 4-slot LDS ring (depth-3 prefetch), 2 fine phases per K-tile, counted
// vmcnt(8), setprio around MFMA clusters. Row stride 64B -> fragment reads
// are inherently bank-balanced (no swizzle needed, linear global_load_lds).
// ---------------------------------------------------------------------------
__global__ __launch_bounds__(512, 2) void gemm_nf4_kernel(
    const ushort_t* __restrict__ A, const ushort_t* __restrict__ Bt,
    const float* __restrict__ bias, float* __restrict__ C)
{
    // 4 slots x (A: 256 rows x 32, B: 256 rows x 32) bf16 = 128 KiB
    __shared__ __align__(16) ushort_t As[4][256 * 32];
    __shared__ __align__(16) ushort_t Bs[4][256 * 32];

    const int tid  = threadIdx.x;
    const int lane = tid & 63;
    const int wid  = tid >> 6;        // 0..7
    const int wr   = wid >> 2;        // 0..1 -> 128-row A strip
    const int wc   = wid & 3;         // 0..3 -> 64-row B strip
    const int ln15 = lane & 15;
    const int lq   = lane >> 4;       // 0..3 (16B k-slot)

    // XCD-aware bijective swizzle (512 % 8 == 0)
    const int wg  = blockIdx.x;
    const int swz = (wg & 7) * 64 + (wg >> 3);
    const int m0  = (swz >> 4) * 256;   // 32 m-tiles
    const int n0  = (swz & 15) * 256;   // 16 n-tiles

    // staging source pointers: thread -> row wid*16 + (lane>>2), col (lane&3)*8
    const int srow = wid * 16 + (lane >> 2);
    const int scol = (lane & 3) * 8;
    const ushort_t* gA0 = A  + (size_t)(m0 + srow) * 4096 + scol;
    const ushort_t* gA1 = gA0 + (size_t)128 * 4096;
    const ushort_t* gB0 = Bt + (size_t)(n0 + srow) * 4096 + scol;
    const ushort_t* gB1 = gB0 + (size_t)128 * 4096;
    const int ldsOff0 = (wid * 16) * 32;          // elements
    const int ldsOff1 = (128 + wid * 16) * 32;

    f32x4 acc[8][4];
    #pragma unroll
    for (int i = 0; i < 8; ++i)
        #pragma unroll
        for (int j = 0; j < 4; ++j)
            acc[i][j] = (f32x4){0.f, 0.f, 0.f, 0.f};

    // per-lane fragment read bases (elements)
    const int rdA = (wr * 128 + ln15) * 32 + lq * 8;
    const int rdB = (wc * 64  + ln15) * 32 + lq * 8;

    // prologue: stage tiles 0,1,2 into slots 0,1,2; wait tile 0
    #pragma unroll
    for (int tt = 0; tt < 3; ++tt) {
        const int kof = tt * 32;
        GLDS16(gA0 + kof, &As[tt][ldsOff0]);
        GLDS16(gA1 + kof, &As[tt][ldsOff1]);
        GLDS16(gB0 + kof, &Bs[tt][ldsOff0]);
        GLDS16(gB1 + kof, &Bs[tt][ldsOff1]);
    }
    asm volatile("s_waitcnt vmcnt(8)" ::: "memory");
    __builtin_amdgcn_s_barrier();
    asm volatile("" ::: "memory");

    for (int t = 0; t < 128; ++t) {
        const int slot = t & 3;
        const ushort_t* Asl = &As[slot][0];
        const ushort_t* Bsl = &Bs[slot][0];

        // ================= phase 1: bf + af0 reads, stage A of t+3 ========
        bf16x8 bf[4], af0[4], af1[4];
        #pragma unroll
        for (int j = 0; j < 4; ++j)
            bf[j] = *reinterpret_cast<const bf16x8*>(Bsl + rdB + j * 16 * 32);
        #pragma unroll
        for (int i = 0; i < 4; ++i)
            af0[i] = *reinterpret_cast<const bf16x8*>(Asl + rdA + i * 16 * 32);
        if (t < 125) {
            const int nslot = (t + 3) & 3;
            const int kof = (t + 3) * 32;
            GLDS16(gA0 + kof, &As[nslot][ldsOff0]);
            GLDS16(gA1 + kof, &As[nslot][ldsOff1]);
        }
        asm volatile("" ::: "memory");
        __builtin_amdgcn_s_barrier();
        asm volatile("s_waitcnt lgkmcnt(0)" ::: "memory");
        __builtin_amdgcn_sched_barrier(0);
        __builtin_amdgcn_s_setprio(1);
        #pragma unroll
        for (int i = 0; i < 4; ++i)
            #pragma unroll
            for (int j = 0; j < 4; ++j)
                acc[i][j] = __builtin_amdgcn_mfma_f32_16x16x32_bf16(
                    af0[i], bf[j], acc[i][j], 0, 0, 0);
        __builtin_amdgcn_s_setprio(0);
        asm volatile("" ::: "memory");
        __builtin_amdgcn_s_barrier();
        asm volatile("" ::: "memory");

        // ================= phase 2: af1 reads, stage B of t+3, vmcnt ======
        #pragma unroll
        for (int i = 0; i < 4; ++i)
            af1[i] = *reinterpret_cast<const bf16x8*>(Asl + rdA + (64 + i * 16) * 32);
        if (t < 125) {
            const int nslot = (t + 3) & 3;
            const int kof = (t + 3) * 32;
            GLDS16(gB0 + kof, &Bs[nslot][ldsOff0]);
            GLDS16(gB1 + kof, &Bs[nslot][ldsOff1]);
            asm volatile("s_waitcnt vmcnt(8)" ::: "memory");   // tile t+1 landed
        } else if (t == 125) {
            asm volatile("s_waitcnt vmcnt(0)" ::: "memory");   // tail drain
        }
        asm volatile("" ::: "memory");
        __builtin_amdgcn_s_barrier();
        asm volatile("s_waitcnt lgkmcnt(0)" ::: "memory");
        __builtin_amdgcn_sched_barrier(0);
        __builtin_amdgcn_s_setprio(1);
        #pragma unroll
        for (int i = 0; i < 4; ++i)
            #pragma unroll
            for (int j = 0; j < 4; ++j)
                acc[4 + i][j] = __builtin_amdgcn_mfma_f32_16x16x32_bf16(
                    af1[i], bf[j], acc[4 + i][j], 0, 0, 0);
        __builtin_amdgcn_s_setprio(0);
        asm volatile("" ::: "memory");
        __builtin_amdgcn_s_barrier();
        asm volatile("" ::: "memory");
    }

    // epilogue: C/D layout col = lane&15, row = (lane>>4)*4 + v
    const int crow0 = m0 + wr * 128 + lq * 4;
    const int ccol0 = n0 + wc * 64 + ln15;
    #pragma unroll
    for (int j = 0; j < 4; ++j) {
        const int c = ccol0 + j * 16;
        const float bv = bias[c];
        #pragma unroll
        for (int i = 0; i < 8; ++i) {
            const int r0 = crow0 + i * 16;
            #pragma unroll
            for (int v = 0; v < 4; ++v)
                C[(size_t)(r0 + v) * 4096 + c] = acc[i][j][v] + bv;
        }
    }
}

// ---------------------------------------------------------------------------
extern "C" void kernel_launch(void* const* d_in, const int* in_sizes, int n_in,
                              void* d_out, int out_size, void* d_ws, size_t ws_size,
                              hipStream_t stream) {
    const float* x      = (const float*)d_in[0];   // [4,2048,4096] fp32
    const int*   q      = (const int*)d_in[1];     // [8388608] byte values
    const float* scales = (const float*)d_in[2];   // [262144]
    const float* bias   = (const float*)d_in[3];   // [4096]
    float* out = (float*)d_out;                    // [8192][4096] fp32

    ushort_t* xb = (ushort_t*)d_ws;                                     // 64 MB bf16 x
    ushort_t* Wt = (ushort_t*)((char*)d_ws + (size_t)64 * 1024 * 1024); // 32 MB bf16 W^T

    cast_x_kernel<<<16384, 256, 0, stream>>>(x, xb);
    nf4_dequant_t_kernel<<<4096, 256, 0, stream>>>(q, scales, Wt);
    gemm_nf4_kernel<<<512, 512, 0, stream>>>(xb, Wt, bias, out);
}

// Round 4
// 307.297 us; speedup vs baseline: 1.2087x; 1.0665x over previous
//
#include <hip/hip_runtime.h>
#include <hip/hip_bf16.h>
#include <stdint.h>

typedef __bf16 bf16x8 __attribute__((ext_vector_type(8)));
typedef float f32x4 __attribute__((ext_vector_type(4)));
typedef unsigned short ushort_t;
typedef ushort_t ushort8 __attribute__((ext_vector_type(8)));

#define GLDS16(g, l) __builtin_amdgcn_global_load_lds(                          \
    (const __attribute__((address_space(1))) void*)(g),                         \
    (__attribute__((address_space(3))) void*)(l), 16, 0, 0)

__device__ __constant__ float NF4_LUT_C[16] = {
    -1.0f, -0.6961928009986877f, -0.5250730514526367f, -0.39491748809814453f,
    -0.28444138169288635f, -0.18477343022823334f, -0.09105003625154495f, 0.0f,
    0.07958029955625534f, 0.16093020141124725f, 0.24611230194568634f,
    0.33791524171829224f, 0.44070982933044434f, 0.5626170039176941f,
    0.7229568362236023f, 1.0f};

__device__ inline ushort_t f32_to_bf16(float f) {
    uint32_t u = __builtin_bit_cast(uint32_t, f);
    u += 0x7FFFu + ((u >> 16) & 1u);
    return (ushort_t)(u >> 16);
}

// ---------------------------------------------------------------------------
// Kernel 1: cast x (fp32) -> bf16, 8 elems/thread
// ---------------------------------------------------------------------------
__global__ __launch_bounds__(256) void cast_x_kernel(
    const float* __restrict__ x, ushort_t* __restrict__ xb)
{
    const int i = blockIdx.x * 256 + threadIdx.x;
    const float4* p = reinterpret_cast<const float4*>(x);
    float4 a = p[i * 2];
    float4 b = p[i * 2 + 1];
    ushort8 v;
    v[0] = f32_to_bf16(a.x); v[1] = f32_to_bf16(a.y);
    v[2] = f32_to_bf16(a.z); v[3] = f32_to_bf16(a.w);
    v[4] = f32_to_bf16(b.x); v[5] = f32_to_bf16(b.y);
    v[6] = f32_to_bf16(b.z); v[7] = f32_to_bf16(b.w);
    *reinterpret_cast<ushort8*>(xb + (size_t)i * 8) = v;
}

// ---------------------------------------------------------------------------
// Kernel 2: NF4 dequant + transpose -> Wt[n][k] bf16  (unchanged, verified)
// ---------------------------------------------------------------------------
__global__ __launch_bounds__(256) void nf4_dequant_t_kernel(
    const int* __restrict__ q, const float* __restrict__ scales,
    ushort_t* __restrict__ Wt)
{
    __shared__ float lut[16];
    __shared__ ushort_t tile[64][65];
    const int t = threadIdx.x;
    if (t < 16) lut[t] = NF4_LUT_C[t];
    __syncthreads();

    const int nt = blockIdx.x & 63;
    const int kt = blockIdx.x >> 6;

    #pragma unroll
    for (int L = t; L < 512; L += 256) {
        const int r  = L >> 3;
        const int qd = L & 7;
        const int k  = kt * 64 + r;
        const int4 e4 = *reinterpret_cast<const int4*>(q + (size_t)k * 2048 + nt * 32 + qd * 4);
        const float s = scales[k * 64 + nt];
        const int nb = qd * 8;
        int bts[4] = {e4.x, e4.y, e4.z, e4.w};
        #pragma unroll
        for (int e = 0; e < 4; ++e) {
            const int byte = bts[e];
            tile[r][nb + e * 2]     = f32_to_bf16(lut[(byte >> 4) & 0xF] * s);
            tile[r][nb + e * 2 + 1] = f32_to_bf16(lut[byte & 0xF] * s);
        }
    }
    __syncthreads();

    const int nl = t >> 2;
    const int ks = (t & 3) * 16;
    ushort8 v0, v1;
    #pragma unroll
    for (int j = 0; j < 8; ++j) v0[j] = tile[ks + j][nl];
    #pragma unroll
    for (int j = 0; j < 8; ++j) v1[j] = tile[ks + 8 + j][nl];
    ushort_t* dst = Wt + (size_t)(nt * 64 + nl) * 4096 + kt * 64 + ks;
    *reinterpret_cast<ushort8*>(dst)     = v0;
    *reinterpret_cast<ushort8*>(dst + 8) = v1;
}

// ---------------------------------------------------------------------------
// Kernel 3: bf16 GEMM, 256x256 tile, BK=32, 8 waves (2M x 4N).
// 4-slot LDS ring, depth-3 prefetch, counted vmcnt(8), ONE barrier per
// K-tile. LDS slot-swizzle: phys_slot = slot ^ ((row>>1)&3) -- within each
// 16-lane fragment-read group, rows spread 2-per-group over all 8 16B bank
// groups (free). global_load_lds stays linear; the GLOBAL source address is
// pre-swizzled with the same involution (rule #21).
// ---------------------------------------------------------------------------
__global__ __launch_bounds__(512, 2) void gemm_nf4_kernel(
    const ushort_t* __restrict__ A, const ushort_t* __restrict__ Bt,
    const float* __restrict__ bias, float* __restrict__ C)
{
    // 4 slots x (A: 256x32, B: 256x32) bf16 = 128 KiB
    __shared__ __align__(16) ushort_t As[4][256 * 32];
    __shared__ __align__(16) ushort_t Bs[4][256 * 32];

    const int tid  = threadIdx.x;
    const int lane = tid & 63;
    const int wid  = tid >> 6;        // 0..7
    const int wr   = wid >> 2;        // 0..1 -> 128-row A strip
    const int wc   = wid & 3;         // 0..3 -> 64-row B strip
    const int ln15 = lane & 15;
    const int lq   = lane >> 4;       // 0..3 (16B k-slot)

    // XCD-aware bijective swizzle (512 % 8 == 0)
    const int wg  = blockIdx.x;
    const int swz = (wg & 7) * 64 + (wg >> 3);
    const int m0  = (swz >> 4) * 256;   // 32 m-tiles
    const int n0  = (swz & 15) * 256;   // 16 n-tiles

    // staging: thread -> LDS row wid*16 + (lane>>2), phys slot lane&3 (linear)
    // source k-offset pre-swizzled: logical slot = (lane&3) ^ ((row>>1)&3),
    // and (row>>1)&3 == (lane>>3)&3 for row = wid*16 + (lane>>2).
    const int srow = wid * 16 + (lane >> 2);
    const int scol = ((lane & 3) ^ ((lane >> 3) & 3)) * 8;
    const ushort_t* gA0 = A  + (size_t)(m0 + srow) * 4096 + scol;
    const ushort_t* gA1 = gA0 + (size_t)128 * 4096;
    const ushort_t* gB0 = Bt + (size_t)(n0 + srow) * 4096 + scol;
    const ushort_t* gB1 = gB0 + (size_t)128 * 4096;
    const int ldsOff0 = (wid * 16) * 32;
    const int ldsOff1 = (128 + wid * 16) * 32;

    f32x4 acc[8][4];
    #pragma unroll
    for (int i = 0; i < 8; ++i)
        #pragma unroll
        for (int j = 0; j < 4; ++j)
            acc[i][j] = (f32x4){0.f, 0.f, 0.f, 0.f};

    // fragment read bases; swizzled k-slot offset is per-lane constant:
    // po = (lq ^ ((row>>1)&3))*8 and (row>>1)&3 == (ln15>>1)&3 for all frags
    const int po  = ((lq ^ ((ln15 >> 1) & 3)) << 3);
    const int rdA = (wr * 128 + ln15) * 32 + po;
    const int rdB = (wc * 64  + ln15) * 32 + po;

    // prologue: stage tiles 0,1,2 into slots 0,1,2; wait tile 0
    #pragma unroll
    for (int tt = 0; tt < 3; ++tt) {
        const int kof = tt * 32;
        GLDS16(gA0 + kof, &As[tt][ldsOff0]);
        GLDS16(gA1 + kof, &As[tt][ldsOff1]);
        GLDS16(gB0 + kof, &Bs[tt][ldsOff0]);
        GLDS16(gB1 + kof, &Bs[tt][ldsOff1]);
    }
    asm volatile("s_waitcnt vmcnt(8)" ::: "memory");
    __builtin_amdgcn_s_barrier();
    __builtin_amdgcn_sched_barrier(0);

    for (int t = 0; t < 128; ++t) {
        const int slot = t & 3;
        const ushort_t* Asl = &As[slot][0];
        const ushort_t* Bsl = &Bs[slot][0];
        const int nslot = (t + 3) & 3;
        const int kof   = (t + 3) * 32;

        // ---- reads for first MFMA cluster + stage A of tile t+3 ----
        bf16x8 bf[4], af0[4], af1[4];
        #pragma unroll
        for (int j = 0; j < 4; ++j)
            bf[j] = *reinterpret_cast<const bf16x8*>(Bsl + rdB + j * 16 * 32);
        #pragma unroll
        for (int i = 0; i < 4; ++i)
            af0[i] = *reinterpret_cast<const bf16x8*>(Asl + rdA + i * 16 * 32);
        if (t < 125) {
            GLDS16(gA0 + kof, &As[nslot][ldsOff0]);
            GLDS16(gA1 + kof, &As[nslot][ldsOff1]);
        }
        __builtin_amdgcn_s_setprio(1);
        #pragma unroll
        for (int i = 0; i < 4; ++i)
            #pragma unroll
            for (int j = 0; j < 4; ++j)
                acc[i][j] = __builtin_amdgcn_mfma_f32_16x16x32_bf16(
                    af0[i], bf[j], acc[i][j], 0, 0, 0);
        __builtin_amdgcn_s_setprio(0);

        // ---- reads for second MFMA cluster + stage B of tile t+3 ----
        #pragma unroll
        for (int i = 0; i < 4; ++i)
            af1[i] = *reinterpret_cast<const bf16x8*>(Asl + rdA + (64 + i * 16) * 32);
        if (t < 125) {
            GLDS16(gB0 + kof, &Bs[nslot][ldsOff0]);
            GLDS16(gB1 + kof, &Bs[nslot][ldsOff1]);
        }
        __builtin_amdgcn_s_setprio(1);
        #pragma unroll
        for (int i = 0; i < 4; ++i)
            #pragma unroll
            for (int j = 0; j < 4; ++j)
                acc[4 + i][j] = __builtin_amdgcn_mfma_f32_16x16x32_bf16(
                    af1[i], bf[j], acc[4 + i][j], 0, 0, 0);
        __builtin_amdgcn_s_setprio(0);

        // ---- tile-boundary sync: own prefetch counted, then one barrier ----
        if (t < 125)       asm volatile("s_waitcnt vmcnt(8)" ::: "memory");
        else if (t == 125) asm volatile("s_waitcnt vmcnt(4)" ::: "memory");
        else if (t == 126) asm volatile("s_waitcnt vmcnt(0)" ::: "memory");
        __builtin_amdgcn_s_barrier();
        __builtin_amdgcn_sched_barrier(0);
    }

    // epilogue: C/D layout col = lane&15, row = (lane>>4)*4 + v
    const int crow0 = m0 + wr * 128 + lq * 4;
    const int ccol0 = n0 + wc * 64 + ln15;
    #pragma unroll
    for (int j = 0; j < 4; ++j) {
        const int c = ccol0 + j * 16;
        const float bv = bias[c];
        #pragma unroll
        for (int i = 0; i < 8; ++i) {
            const int r0 = crow0 + i * 16;
            #pragma unroll
            for (int v = 0; v < 4; ++v)
                C[(size_t)(r0 + v) * 4096 + c] = acc[i][j][v] + bv;
        }
    }
}

// ---------------------------------------------------------------------------
extern "C" void kernel_launch(void* const* d_in, const int* in_sizes, int n_in,
                              void* d_out, int out_size, void* d_ws, size_t ws_size,
                              hipStream_t stream) {
    const float* x      = (const float*)d_in[0];   // [4,2048,4096] fp32
    const int*   q      = (const int*)d_in[1];     // [8388608] byte values
    const float* scales = (const float*)d_in[2];   // [262144]
    const float* bias   = (const float*)d_in[3];   // [4096]
    float* out = (float*)d_out;                    // [8192][4096] fp32

    ushort_t* xb = (ushort_t*)d_ws;                                     // 64 MB bf16 x
    ushort_t* Wt = (ushort_t*)((char*)d_ws + (size_t)64 * 1024 * 1024); // 32 MB bf16 W^T

    cast_x_kernel<<<16384, 256, 0, stream>>>(x, xb);
    nf4_dequant_t_kernel<<<4096, 256, 0, stream>>>(q, scales, Wt);
    gemm_nf4_kernel<<<512, 512, 0, stream>>>(xb, Wt, bias, out);
}